// Round 7
// baseline (584.263 us; speedup 1.0000x reference)
//
#include <hip/hip_runtime.h>
#include <math.h>

#define T 32
#define K 2048
#define NBLOCKS 256
#define NTHREADS 512
#define NWAVES 8
#define CPB 8                           // columns per block (1 per wave)
#define QS 4                            // K / NTHREADS slots per thread
#define L2E_F 1.4426950408889634f       // log2(e)
#define LN2_F 0.6931471805599453f
#define LOG2PI_F 1.8378770664093453f
#define LOG_K_F  7.6246189861593985f    // ln(2048)
#define SP_F     0.17677669529663687f   // sqrt(1/32)
#define LOG_SP_F (-1.7328679513998633f) // ln(sqrt(1/32))

#if __has_builtin(__builtin_amdgcn_exp2f)
#define EXP2F(x) __builtin_amdgcn_exp2f(x)
#else
#define EXP2F(x) exp2f(x)
#endif
#if __has_builtin(__builtin_amdgcn_logf)
#define LOG2F(x) __builtin_amdgcn_logf(x)
#else
#define LOG2F(x) log2f(x)
#endif

// relaxed agent-scope atomics: bypass non-coherent L1/L2, land at the MALL.
__device__ __forceinline__ float aload4(const float* p) {
    return __hip_atomic_load(p, __ATOMIC_RELAXED, __HIP_MEMORY_SCOPE_AGENT);
}
__device__ __forceinline__ void astore4(float* p, float v) {
    __hip_atomic_store(p, v, __ATOMIC_RELAXED, __HIP_MEMORY_SCOPE_AGENT);
}
__device__ __forceinline__ unsigned int aloadw(const unsigned int* p) {
    return __hip_atomic_load(p, __ATOMIC_RELAXED, __HIP_MEMORY_SCOPE_AGENT);
}
__device__ __forceinline__ void astore_flag(unsigned char* p, unsigned char v) {
    __hip_atomic_store(p, v, __ATOMIC_RELEASE, __HIP_MEMORY_SCOPE_AGENT);
}

// Fully fused dataflow chain, flag-gated. 256 blocks x 512 threads; block b
// owns columns [8b, 8b+8), one per wave. Protocol per step: poll 256 byte
// flags (4 cachelines) until all == step-tag, then one-shot bulk read of the
// 2048-float r-row (safe non-repeated reads: producer data stores complete
// before its flag store — per-wave data store + __syncthreads vmcnt drain +
// release flag). Two ping-pong data+flag arrays suffice by the
// full-consumption-before-production invariant (see R3): flag[par][b] can
// only advance from s+1 to s+3 after every block passed its ==s+1 poll.
// Flag values 1..33 never collide with the 0xAA workspace poison.
// Chain state is carried in log2 domain (rho = r * log2e): inner fma
// unchanged, exp2/log2 are single native V_EXP/V_LOG ops, log2(K) = 11.
__global__ __launch_bounds__(NTHREADS) void fused_kernel(
    const float* __restrict__ means, const float* __restrict__ log_stds,
    const float* __restrict__ eps, float* __restrict__ rbuf,
    unsigned char* __restrict__ flags, float* __restrict__ out)
{
    __shared__ float2 shzr[2][K];    // 32 KB: (z_j, R2_j = rho_j - 16*L2E*z_j^2)
    __shared__ float2 lzc[T][CPB];   // own cols: (tz2 = 32*L2E*z', cm2)
    __shared__ float smu[T], sstd[T];
    __shared__ float red[NTHREADS];

    const int tid  = threadIdx.x;
    const int b    = blockIdx.x;
    const int col0 = b * CPB;

    // ---- setup: threads 0..255, thread (t = tid>>3, dcol = tid&7) ----
    if (tid < T * CPB) {
        int t = tid >> 3, dcol = tid & 7;
        float mu = means[t];
        float st = expf(log_stds[t]);
        if (dcol == 0) { smu[t] = mu; sstd[t] = st; }
        float e = eps[t * K + col0 + dcol];
        float z = fmaf(st, e, mu);
        // (z-mu)/st == e exactly: log_q = -0.5 e^2 - ln(st) - 0.5 ln2pi
        float log_q = fmaf(-0.5f * e, e, -logf(st) - 0.5f * LOG2PI_F);
        float ct = -LOG_SP_F - 0.5f * LOG2PI_F - log_q;
        float tz2 = (32.0f * L2E_F) * z;
        float cm2 = fmaf((-16.0f * L2E_F) * z, z, L2E_F * ct) - 11.0f; // log2K=11
        lzc[t][dcol] = make_float2(tz2, cm2);
        if (t == 0) {
            float zz = z / SP_F;
            float r0 = -0.5f * zz * zz - LOG_SP_F - 0.5f * LOG2PI_F - log_q;
            astore4(&rbuf[col0 + dcol], r0 * L2E_F);   // rho_0, parity 0
        }
    }
    // r0 stores were wave 0 (tids 0..7); thread 0's release store waits the
    // wave's vmcnt before issuing -> data precedes flag at the MALL.
    if (tid == 0) astore_flag(&flags[0 * NBLOCKS + b], 1);
    __syncthreads();

    const int lane = tid & 63;
    const int wave = tid >> 6;           // 0..7: column col0 + wave

    for (int s = 0; s < T - 1; ++s) {
        const int par = s & 1;
        const float mu_s  = smu[s];
        const float std_s = sstd[s];
        const float* erow = eps + s * K;

        // ---- pre-poll: z and -16*L2E*z^2 in registers (r-independent) ----
        float zloc[QS], nz2[QS];
        #pragma unroll
        for (int q = 0; q < QS; ++q) {
            float e = erow[tid + q * NTHREADS];
            float z = fmaf(std_s, e, mu_s);
            zloc[q] = z;
            nz2[q]  = ((-16.0f * L2E_F) * z) * z;
        }

        // ---- poll the 4-cacheline flag array (per wave, 1 word/lane) ----
        const unsigned int pat = (unsigned int)(s + 1) * 0x01010101u;
        const unsigned int* fw = (const unsigned int*)(flags + par * NBLOCKS);
        unsigned int w = aloadw(&fw[lane]);
        while (!__all(w == pat)) {
            __builtin_amdgcn_s_sleep(1);
            w = aloadw(&fw[lane]);
        }

        // ---- one-shot bulk read of the rho-row (flag-gated, no re-sweep) ----
        const float* rrow = rbuf + par * K;
        float rv[QS];
        #pragma unroll
        for (int q = 0; q < QS; ++q) rv[q] = aload4(&rrow[tid + q * NTHREADS]);

        // ---- stage (z, R2) pairs: single b64 writes, conflict-free ----
        #pragma unroll
        for (int q = 0; q < QS; ++q)
            shzr[par][tid + q * NTHREADS] = make_float2(zloc[q], rv[q] + nz2[q]);
        __syncthreads();

        // ---- pull this lane's 32 j's as 16 b128 reads ----
        const float4* shp = (const float4*)&shzr[par][0];
        float4 f4[16];
        #pragma unroll
        for (int i = 0; i < 16; ++i) f4[i] = shp[lane + 64 * i];

        // ---- this wave's column: max pass + exp2 pass ----
        float2 zc = lzc[s + 1][wave];
        float tz2 = zc.x, cm2 = zc.y;
        float m = -INFINITY;
        #pragma unroll
        for (int i = 0; i < 16; ++i) {
            // u_j = rho_j - 16*L2E*(z'-z_j)^2 + 16*L2E*z'^2 = fma(tz2, z_j, R2_j)
            m = fmaxf(m, fmaf(tz2, f4[i].x, f4[i].y));
            m = fmaxf(m, fmaf(tz2, f4[i].z, f4[i].w));
        }
        #pragma unroll
        for (int off = 32; off >= 1; off >>= 1)
            m = fmaxf(m, __shfl_xor(m, off, 64));
        float ss = 0.0f;
        #pragma unroll
        for (int i = 0; i < 16; ++i) {
            ss += EXP2F(fmaf(tz2, f4[i].x, f4[i].y) - m);
            ss += EXP2F(fmaf(tz2, f4[i].z, f4[i].w) - m);
        }
        #pragma unroll
        for (int off = 32; off >= 1; off >>= 1)
            ss += __shfl_xor(ss, off, 64);
        if (lane == 0)
            astore4(&rbuf[(par ^ 1) * K + col0 + wave], cm2 + m + LOG2F(ss));

        // barrier #2: every wave's publish store is vmcnt-drained before
        // s_barrier, so after it ALL 8 column stores are at the MALL ...
        __syncthreads();
        // ... and only then the block's flag advances.
        if (tid == 0)
            astore_flag(&flags[(par ^ 1) * NBLOCKS + b], (unsigned char)(s + 2));
    }

    // ---- final logmeanexp over r_31 + likelihood, block 0 only ----
    if (b == 0) {
        const unsigned int pat = (unsigned int)T * 0x01010101u;  // 0x20202020
        const unsigned int* fw = (const unsigned int*)(flags + 1 * NBLOCKS);
        unsigned int w = aloadw(&fw[lane]);
        while (!__all(w == pat)) {
            __builtin_amdgcn_s_sleep(1);
            w = aloadw(&fw[lane]);
        }
        const float* rrow = rbuf + 1 * K;       // rho_31 lives in parity 1
        const float* erow = eps + (T - 1) * K;
        const float mu_l  = smu[T - 1];
        const float std_l = sstd[T - 1];
        float vals[QS];
        float m = -INFINITY;
        #pragma unroll
        for (int q = 0; q < QS; ++q) {
            int j = tid + q * NTHREADS;
            float r = aload4(&rrow[j]) * LN2_F;  // back to natural log
            float z = fmaf(std_l, erow[j], mu_l);
            float d = 0.5f - z;
            float v = r + fmaf(-0.5f * d, d, -0.5f * LOG2PI_F);
            vals[q] = v;
            m = fmaxf(m, v);
        }
        red[tid] = m; __syncthreads();
        for (int off = NTHREADS / 2; off >= 1; off >>= 1) {
            if (tid < off) red[tid] = fmaxf(red[tid], red[tid + off]);
            __syncthreads();
        }
        m = red[0]; __syncthreads();
        float ssum = 0.0f;
        #pragma unroll
        for (int q = 0; q < QS; ++q) ssum += __expf(vals[q] - m);
        red[tid] = ssum; __syncthreads();
        for (int off = NTHREADS / 2; off >= 1; off >>= 1) {
            if (tid < off) red[tid] += red[tid + off];
            __syncthreads();
        }
        if (tid == 0) out[0] = m + logf(red[0]) - LOG_K_F;
    }
}

extern "C" void kernel_launch(void* const* d_in, const int* in_sizes, int n_in,
                              void* d_out, int out_size, void* d_ws, size_t ws_size,
                              hipStream_t stream) {
    const float* means    = (const float*)d_in[0];
    const float* log_stds = (const float*)d_in[1];
    const float* eps      = (const float*)d_in[2];
    float* out = (float*)d_out;

    float* rbuf = (float*)d_ws;                       // 2*K rho ping-pong (16 KB)
    unsigned char* flags = (unsigned char*)(rbuf + 2 * K);  // 2*256 byte flags

    fused_kernel<<<NBLOCKS, NTHREADS, 0, stream>>>(
        means, log_stds, eps, rbuf, flags, out);
}

// Round 8
// 149.962 us; speedup vs baseline: 3.8961x; 3.8961x over previous
//
#include <hip/hip_runtime.h>
#include <math.h>

#define T 32
#define K 2048
#define NBLOCKS 256
#define NTHREADS 512
#define CPB 8                           // columns per block (1 per wave)
#define QS 4                            // K / NTHREADS slots per thread
#define SENT_STRIDE 32                  // ints: 128 B -> one MALL line per sentinel
#define L2E_F 1.4426950408889634f       // log2(e)
#define LN2_F 0.6931471805599453f
#define LOG2PI_F 1.8378770664093453f
#define LOG_K_F  7.6246189861593985f    // ln(2048)
#define SP_F     0.17677669529663687f   // sqrt(1/32)
#define LOG_SP_F (-1.7328679513998633f) // ln(sqrt(1/32))

#if __has_builtin(__builtin_amdgcn_exp2f)
#define EXP2F(x) __builtin_amdgcn_exp2f(x)
#else
#define EXP2F(x) exp2f(x)
#endif
#if __has_builtin(__builtin_amdgcn_logf)
#define LOG2F(x) __builtin_amdgcn_logf(x)
#else
#define LOG2F(x) log2f(x)
#endif

// ALL global sync traffic is relaxed agent-scope atomics: write-through to
// the MALL, bypassing the non-coherent per-XCD L2s. NO release/acquire at
// agent scope anywhere (R2/R7 showed those cost ~15us/step in L2
// cache-maintenance). Producer ordering (data before sentinel) comes from
// __syncthreads' per-wave vmcnt drain before s_barrier.
__device__ __forceinline__ float aload4(const float* p) {
    return __hip_atomic_load(p, __ATOMIC_RELAXED, __HIP_MEMORY_SCOPE_AGENT);
}
__device__ __forceinline__ void astore4(float* p, float v) {
    __hip_atomic_store(p, v, __ATOMIC_RELAXED, __HIP_MEMORY_SCOPE_AGENT);
}
__device__ __forceinline__ int sload(const int* p) {
    return __hip_atomic_load(p, __ATOMIC_RELAXED, __HIP_MEMORY_SCOPE_AGENT);
}
__device__ __forceinline__ void sstore(int* p, int v) {
    __hip_atomic_store(p, v, __ATOMIC_RELAXED, __HIP_MEMORY_SCOPE_AGENT);
}

// Fully fused dataflow chain, sentinel-gated one-shot reads.
// 256 blocks x 512 threads; block b owns columns [8b, 8b+8), one per wave.
// Per step: wave 0 polls 256 per-producer sentinels (each on its own 128B
// line; signed values 1..32, so the negative 0xAAAAAAAA poison never
// satisfies >=), hands off via an LDS flag (workgroup scope: lgkmcnt only),
// then the whole block bulk-reads the 2048-float rho-row EXACTLY ONCE.
// Safety of >= and the 2-row ping-pong: sentinel spread across blocks is at
// most 1 step (advancing to s+2 requires having observed ALL sentinels
// >= s+1, which requires every block's step-s+1 data published, which
// required consuming step s) — a row is never overwritten while readable.
__global__ __launch_bounds__(NTHREADS) void fused_kernel(
    const float* __restrict__ means, const float* __restrict__ log_stds,
    const float* __restrict__ eps, float* __restrict__ rbuf,
    int* __restrict__ sent, float* __restrict__ out)
{
    __shared__ float2 shzr[2][K];    // 32 KB: (z_j, R2_j = rho_j - 16*L2E*z_j^2)
    __shared__ float2 lzc[T][CPB];   // own cols: (tz2 = 32*L2E*z', cm2)
    __shared__ float smu[T], sstd[T];
    __shared__ float red[NTHREADS];
    __shared__ int ldsflag;

    const int tid  = threadIdx.x;
    const int b    = blockIdx.x;
    const int col0 = b * CPB;

    if (tid == 0) ldsflag = 0;

    // ---- setup: threads 0..255, thread (t = tid>>3, dcol = tid&7) ----
    if (tid < T * CPB) {
        int t = tid >> 3, dcol = tid & 7;
        float mu = means[t];
        float st = expf(log_stds[t]);
        if (dcol == 0) { smu[t] = mu; sstd[t] = st; }
        float e = eps[t * K + col0 + dcol];
        float z = fmaf(st, e, mu);
        // (z-mu)/st == e exactly: log_q = -0.5 e^2 - ln(st) - 0.5 ln2pi
        float log_q = fmaf(-0.5f * e, e, -logf(st) - 0.5f * LOG2PI_F);
        float ct = -LOG_SP_F - 0.5f * LOG2PI_F - log_q;
        float tz2 = (32.0f * L2E_F) * z;
        float cm2 = fmaf((-16.0f * L2E_F) * z, z, L2E_F * ct) - 11.0f; // log2K=11
        lzc[t][dcol] = make_float2(tz2, cm2);
        if (t == 0) {
            float zz = z / SP_F;
            float r0 = -0.5f * zz * zz - LOG_SP_F - 0.5f * LOG2PI_F - log_q;
            astore4(&rbuf[col0 + dcol], r0 * L2E_F);   // rho_0, parity 0
        }
    }
    __syncthreads();                      // drains r0 stores (vmcnt) + lzc/ldsflag
    if (tid == 0) sstore(&sent[b * SENT_STRIDE], 1);

    const int lane = tid & 63;
    const int wave = tid >> 6;            // 0..7: column col0 + wave

    for (int s = 0; s < T - 1; ++s) {
        const int par = s & 1;
        const int need = s + 1;
        const float mu_s  = smu[s];
        const float std_s = sstd[s];
        const float* erow = eps + s * K;

        // ---- pre-detect: z and -16*L2E*z^2 in registers (r-independent) ----
        float zloc[QS], nz2[QS];
        #pragma unroll
        for (int q = 0; q < QS; ++q) {
            float e = erow[tid + q * NTHREADS];
            float z = fmaf(std_s, e, mu_s);
            zloc[q] = z;
            nz2[q]  = ((-16.0f * L2E_F) * z) * z;
        }

        // ---- detection: wave 0 polls 256 one-line sentinels, LDS handoff ----
        if (wave == 0) {
            const int* s0 = sent + lane * 4 * SENT_STRIDE;
            for (;;) {
                int v0 = sload(s0);
                int v1 = sload(s0 + SENT_STRIDE);
                int v2 = sload(s0 + 2 * SENT_STRIDE);
                int v3 = sload(s0 + 3 * SENT_STRIDE);
                int mn = min(min(v0, v1), min(v2, v3));
                if (__all(mn >= need)) break;
                __builtin_amdgcn_s_sleep(1);
            }
            __hip_atomic_store(&ldsflag, need, __ATOMIC_RELEASE,
                               __HIP_MEMORY_SCOPE_WORKGROUP);
        } else {
            while (__hip_atomic_load(&ldsflag, __ATOMIC_ACQUIRE,
                                     __HIP_MEMORY_SCOPE_WORKGROUP) < need)
                __builtin_amdgcn_s_sleep(1);
        }

        // ---- one-shot bulk read of the rho-row (sentinel-gated) ----
        const float* rrow = rbuf + par * K;
        float rv[QS];
        #pragma unroll
        for (int q = 0; q < QS; ++q) rv[q] = aload4(&rrow[tid + q * NTHREADS]);

        // ---- stage (z, R2) pairs: b64 writes, conflict-free ----
        #pragma unroll
        for (int q = 0; q < QS; ++q)
            shzr[par][tid + q * NTHREADS] = make_float2(zloc[q], rv[q] + nz2[q]);
        __syncthreads();

        // ---- this wave's column: keep u in regs, max pass then exp2 pass ----
        const float4* shp = (const float4*)&shzr[par][0];
        float2 zc = lzc[s + 1][wave];
        float tz2 = zc.x, cm2 = zc.y;
        float u[32];
        float m = -INFINITY;
        #pragma unroll
        for (int i = 0; i < 16; ++i) {
            float4 f4 = shp[lane + 64 * i];
            // u_j = rho_j - 16*L2E*(z'-z_j)^2 + 16*L2E*z'^2 = fma(tz2, z_j, R2_j)
            u[2 * i]     = fmaf(tz2, f4.x, f4.y);
            u[2 * i + 1] = fmaf(tz2, f4.z, f4.w);
            m = fmaxf(m, fmaxf(u[2 * i], u[2 * i + 1]));
        }
        #pragma unroll
        for (int off = 32; off >= 1; off >>= 1)
            m = fmaxf(m, __shfl_xor(m, off, 64));
        float ss = 0.0f;
        #pragma unroll
        for (int i = 0; i < 32; ++i) ss += EXP2F(u[i] - m);
        #pragma unroll
        for (int off = 32; off >= 1; off >>= 1)
            ss += __shfl_xor(ss, off, 64);
        if (lane == 0)
            astore4(&rbuf[(par ^ 1) * K + col0 + wave], cm2 + m + LOG2F(ss));

        // barrier drains every wave's publish store (vmcnt) before s_barrier;
        // only then the block's sentinel advances (relaxed store).
        __syncthreads();
        if (tid == 0) sstore(&sent[b * SENT_STRIDE], s + 2);
    }

    // ---- final logmeanexp over r_31 + likelihood, block 0 only ----
    if (b == 0) {
        const int* s0 = sent + lane * 4 * SENT_STRIDE;
        for (;;) {   // all waves poll (one-time)
            int v0 = sload(s0);
            int v1 = sload(s0 + SENT_STRIDE);
            int v2 = sload(s0 + 2 * SENT_STRIDE);
            int v3 = sload(s0 + 3 * SENT_STRIDE);
            int mn = min(min(v0, v1), min(v2, v3));
            if (__all(mn >= T)) break;
            __builtin_amdgcn_s_sleep(1);
        }
        const float* rrow = rbuf + 1 * K;       // rho_31 lives in parity 1
        const float* erow = eps + (T - 1) * K;
        const float mu_l  = smu[T - 1];
        const float std_l = sstd[T - 1];
        float vals[QS];
        float m = -INFINITY;
        #pragma unroll
        for (int q = 0; q < QS; ++q) {
            int j = tid + q * NTHREADS;
            float r = aload4(&rrow[j]) * LN2_F;  // back to natural log
            float z = fmaf(std_l, erow[j], mu_l);
            float d = 0.5f - z;
            float v = r + fmaf(-0.5f * d, d, -0.5f * LOG2PI_F);
            vals[q] = v;
            m = fmaxf(m, v);
        }
        red[tid] = m; __syncthreads();
        for (int off = NTHREADS / 2; off >= 1; off >>= 1) {
            if (tid < off) red[tid] = fmaxf(red[tid], red[tid + off]);
            __syncthreads();
        }
        m = red[0]; __syncthreads();
        float ssum = 0.0f;
        #pragma unroll
        for (int q = 0; q < QS; ++q) ssum += __expf(vals[q] - m);
        red[tid] = ssum; __syncthreads();
        for (int off = NTHREADS / 2; off >= 1; off >>= 1) {
            if (tid < off) red[tid] += red[tid + off];
            __syncthreads();
        }
        if (tid == 0) out[0] = m + logf(red[0]) - LOG_K_F;
    }
}

extern "C" void kernel_launch(void* const* d_in, const int* in_sizes, int n_in,
                              void* d_out, int out_size, void* d_ws, size_t ws_size,
                              hipStream_t stream) {
    const float* means    = (const float*)d_in[0];
    const float* log_stds = (const float*)d_in[1];
    const float* eps      = (const float*)d_in[2];
    float* out = (float*)d_out;

    float* rbuf = (float*)d_ws;                 // 2*K rho ping-pong (16 KB)
    int*   sent = (int*)(rbuf + 2 * K);         // 256 sentinels, 128 B apart (32 KB)

    fused_kernel<<<NBLOCKS, NTHREADS, 0, stream>>>(
        means, log_stds, eps, rbuf, sent, out);
}